// Round 18
// baseline (105.395 us; speedup 1.0000x reference)
//
#include <hip/hip_runtime.h>
#include <math.h>

#define Hh 16
#define DH 64
#define NR 33

typedef short s16x8 __attribute__((ext_vector_type(8)));
typedef float f32x4 __attribute__((ext_vector_type(4)));
typedef __fp16 h16x2 __attribute__((ext_vector_type(2)));

static __device__ __forceinline__ short f2h(float f) {
    _Float16 h = (_Float16)f;              // RNE
    short s; __builtin_memcpy(&s, &h, 2); return s;
}
static __device__ __forceinline__ float h2f(short s) {
    _Float16 h; __builtin_memcpy(&h, &s, 2); return (float)h;
}
static __device__ __forceinline__ unsigned pk2h(float a, float b) {
    h16x2 h = __builtin_amdgcn_cvt_pkrtz(a, b);   // packed RTZ, 1 VALU op
    unsigned r; __builtin_memcpy(&r, &h, 4); return r;
}

// MFMA f16, hazard nops inside the asm block: the "+v" output dependency
// orders every consumer after the wait-states.
static __device__ __forceinline__ void mfma16(f32x4& c, const s16x8& a, const s16x8& b) {
    asm("s_nop 3\n\tv_mfma_f32_16x16x32_f16 %0, %1, %2, %0"
        : "+v"(c) : "v"(a), "v"(b));
}
static __device__ __forceinline__ void mfma16_last(f32x4& c, const s16x8& a, const s16x8& b) {
    asm("s_nop 3\n\tv_mfma_f32_16x16x32_f16 %0, %1, %2, %0\n\ts_nop 7\n\ts_nop 7"
        : "+v"(c) : "v"(a), "v"(b));
}
static __device__ __forceinline__ void acc_guard(f32x4& c) {
    asm volatile("s_nop 7\n\ts_nop 7" : "+v"(c));
}

// async global->LDS, 16B/lane (GEMMs only — attn uses register staging)
static __device__ __forceinline__ void gld16(const short* g, short* l) {
    __builtin_amdgcn_global_load_lds(
        (const __attribute__((address_space(1))) void*)g,
        (__attribute__((address_space(3))) void*)l, 16, 0, 0);
}
static __device__ __forceinline__ void drain_vmem() {
    asm volatile("s_waitcnt vmcnt(0)" ::: "memory");
}

// swizzled fragment read: LDS[row][x] holds G[row][x ^ ((row&7)<<4)] (bytes)
static __device__ __forceinline__ s16x8 lds_frag(const short* base, int row, int kb) {
    return *(const s16x8*)((const char*)base + row * 128 + (kb ^ ((row & 7) << 4)));
}

// ---------------- weights: fp32 [K][N] -> f16 [N][K] ------------------------
__global__ __launch_bounds__(256)
void cvt_w(const float* __restrict__ W0, const float* __restrict__ W1,
           const float* __restrict__ W2, const float* __restrict__ W3,
           short* __restrict__ Wt) {
    __shared__ float ts[32][33];
    const int z = blockIdx.z;
    const float* W = (z == 0) ? W0 : (z == 1) ? W1 : (z == 2) ? W2 : W3;
    short* O = Wt + (size_t)z * 1024 * 1024;
    const int n0 = blockIdx.x * 32, k0 = blockIdx.y * 32;
    const int tx = threadIdx.x & 31, ty = threadIdx.x >> 5;
    #pragma unroll
    for (int rr = 0; rr < 4; ++rr)
        ts[ty + 8 * rr][tx] = W[(size_t)(k0 + ty + 8 * rr) * 1024 + n0 + tx];
    __syncthreads();
    #pragma unroll
    for (int rr = 0; rr < 4; ++rr)
        O[(size_t)(n0 + ty + 8 * rr) * 1024 + k0 + tx] = f2h(ts[tx][ty + 8 * rr]);
}

// ---------------- V^T: v16 [b][s][h*64+d] -> vt16 [(b*16+h)*64+d][s] --------
__global__ __launch_bounds__(256)
void vT(const short* __restrict__ v16, short* __restrict__ vt16) {
    __shared__ short ts[64][72];
    const int st = blockIdx.x;      // s-tile (16)
    const int bh = blockIdx.y;      // 32
    const int b = bh >> 4, h = bh & 15;
    const size_t inb = ((size_t)b * 1024 + st * 64) * 1024 + h * 64;
    #pragma unroll
    for (int i = 0; i < 2; ++i) {
        int chunk = i * 256 + threadIdx.x;
        int row = chunk >> 3, c8 = chunk & 7;
        *(s16x8*)&ts[row][c8 * 8] =
            *(const s16x8*)(v16 + inb + (size_t)row * 1024 + c8 * 8);
    }
    __syncthreads();
    const size_t outb = (size_t)(bh * 64) * 1024 + st * 64;
    #pragma unroll
    for (int i = 0; i < 2; ++i) {
        int chunk = i * 256 + threadIdx.x;
        int d = chunk >> 3, c8 = chunk & 7;
        s16x8 t;
        #pragma unroll
        for (int e = 0; e < 8; ++e) t[e] = ts[c8 * 8 + e][d];
        *(s16x8*)(vt16 + outb + (size_t)d * 1024 + c8 * 8) = t;
    }
}

// ---------------- fused QKV projection: f16 MFMA (R7-proven) ----------------
// Slab 0 (Q) output is PRE-SCALED by log2(e)/sqrt(dh): QK^T scores and the
// qr bias then come out of the MFMA already scaled -> attn softmax is a
// single add + exp2 per element.
__global__ __launch_bounds__(256)
void gemm_qkv(const float* __restrict__ Aq, const float* __restrict__ Ak,
              const float* __restrict__ Av, const short* __restrict__ Wt,
              const float* __restrict__ bq, const float* __restrict__ bk,
              const float* __restrict__ bv, short* __restrict__ Out) {
    __shared__ __align__(16) short As[64 * 64];
    __shared__ __align__(16) short Bs[128 * 64];
    const int tid = threadIdx.x;
    const int wave = tid >> 6, lane = tid & 63;
    const int g = lane >> 4, r = lane & 15;
    const int wm = wave >> 1, wn = wave & 1;
    const int n0 = blockIdx.x * 128;
    const int by = blockIdx.y;
    const int slab = by >> 5;                 // 0:q 1:k 2:v
    const int m0 = (by & 31) * 64;
    const float* A    = (slab == 0) ? Aq : (slab == 1) ? Ak : Av;
    const float* bias = (slab == 0) ? bq : (slab == 1) ? bk : bv;
    const float osc   = (slab == 0) ? 0.18033688f : 1.0f;  // log2(e)/8 on Q
    const short* Bg = Wt + (size_t)slab * 1024 * 1024;
    short* Og = Out + (size_t)slab * 2048 * 1024;

    const int ar = tid >> 2, ak = tid & 3;
    const float* ap = A + (size_t)(m0 + ar) * 1024 + ak * 16;
    char* asb = (char*)As + ar * 128;
    const int aswz = (ar & 7) << 4;
    const int ao0 = (ak * 32) ^ aswz, ao1 = (ak * 32 + 16) ^ aswz;

    const short* bp[4]; short* bl[4];
    #pragma unroll
    for (int i = 0; i < 4; ++i) {
        int s = i * 256 + tid;
        int row = s >> 3, sk = s & 7;
        int gb = (sk * 16) ^ ((row & 7) << 4);
        bp[i] = Bg + (size_t)(n0 + row) * 1024 + gb / 2;
        bl[i] = Bs + (size_t)(i * 256 + wave * 64) * 8;
    }

    f32x4 acc[2][4] = {};
    #pragma unroll
    for (int mi = 0; mi < 2; ++mi)
        #pragma unroll
        for (int nj = 0; nj < 4; ++nj)
            asm volatile("s_nop 7" : "+v"(acc[mi][nj]));

    for (int kt = 0; kt < 1024; kt += 64) {
        #pragma unroll
        for (int i = 0; i < 4; ++i) gld16(bp[i] + kt, bl[i]);
        float4 va[4];
        #pragma unroll
        for (int c = 0; c < 4; ++c) va[c] = *(const float4*)(ap + kt + c * 4);
        unsigned pk[8];
        #pragma unroll
        for (int c = 0; c < 4; ++c) {
            pk[2 * c]     = pk2h(va[c].x, va[c].y);
            pk[2 * c + 1] = pk2h(va[c].z, va[c].w);
        }
        *(uint4*)(asb + ao0) = *(const uint4*)&pk[0];
        *(uint4*)(asb + ao1) = *(const uint4*)&pk[4];
        drain_vmem();
        __syncthreads();
        #pragma unroll
        for (int ks = 0; ks < 2; ++ks) {
            s16x8 af[2], bf[4];
            #pragma unroll
            for (int mi = 0; mi < 2; ++mi)
                af[mi] = lds_frag(As, wm * 32 + mi * 16 + r, ks * 64 + g * 16);
            #pragma unroll
            for (int nj = 0; nj < 4; ++nj)
                bf[nj] = lds_frag(Bs, wn * 64 + nj * 16 + r, ks * 64 + g * 16);
            #pragma unroll
            for (int mi = 0; mi < 2; ++mi)
                #pragma unroll
                for (int nj = 0; nj < 4; ++nj)
                    mfma16(acc[mi][nj], af[mi], bf[nj]);
        }
        __syncthreads();
    }
    #pragma unroll
    for (int nj = 0; nj < 4; ++nj) {
        int col = n0 + wn * 64 + nj * 16 + r;
        float bv_ = bias[col];
        #pragma unroll
        for (int mi = 0; mi < 2; ++mi) {
            acc_guard(acc[mi][nj]);
            #pragma unroll
            for (int j = 0; j < 4; ++j) {
                int row = m0 + wm * 32 + mi * 16 + g * 4 + j;
                Og[(size_t)row * 1024 + col] = f2h((acc[mi][nj][j] + bv_) * osc);
            }
        }
    }
}

// ---------------- output projection: x(f16) @ Wo_t(f16) + bo -> fp32 --------
__global__ __launch_bounds__(256)
void gemm_out(const short* __restrict__ Xg, const short* __restrict__ Bg,
              const float* __restrict__ bo, float* __restrict__ Og) {
    __shared__ __align__(16) short As[64 * 64];
    __shared__ __align__(16) short Bs[128 * 64];
    const int tid = threadIdx.x;
    const int wave = tid >> 6, lane = tid & 63;
    const int g = lane >> 4, r = lane & 15;
    const int wm = wave >> 1, wn = wave & 1;
    const int n0 = blockIdx.x * 128;
    const int m0 = blockIdx.y * 64;

    const short* xp[2]; short* xl[2];
    #pragma unroll
    for (int i = 0; i < 2; ++i) {
        int s = i * 256 + tid;
        int row = s >> 3, sk = s & 7;
        int gb = (sk * 16) ^ ((row & 7) << 4);
        xp[i] = Xg + (size_t)(m0 + row) * 1024 + gb / 2;
        xl[i] = As + (size_t)(i * 256 + wave * 64) * 8;
    }
    const short* bp[4]; short* bl[4];
    #pragma unroll
    for (int i = 0; i < 4; ++i) {
        int s = i * 256 + tid;
        int row = s >> 3, sk = s & 7;
        int gb = (sk * 16) ^ ((row & 7) << 4);
        bp[i] = Bg + (size_t)(n0 + row) * 1024 + gb / 2;
        bl[i] = Bs + (size_t)(i * 256 + wave * 64) * 8;
    }

    f32x4 acc[2][4] = {};
    #pragma unroll
    for (int mi = 0; mi < 2; ++mi)
        #pragma unroll
        for (int nj = 0; nj < 4; ++nj)
            asm volatile("s_nop 7" : "+v"(acc[mi][nj]));

    for (int kt = 0; kt < 1024; kt += 64) {
        #pragma unroll
        for (int i = 0; i < 2; ++i) gld16(xp[i] + kt, xl[i]);
        #pragma unroll
        for (int i = 0; i < 4; ++i) gld16(bp[i] + kt, bl[i]);
        drain_vmem();
        __syncthreads();
        #pragma unroll
        for (int ks = 0; ks < 2; ++ks) {
            s16x8 af[2], bf[4];
            #pragma unroll
            for (int mi = 0; mi < 2; ++mi)
                af[mi] = lds_frag(As, wm * 32 + mi * 16 + r, ks * 64 + g * 16);
            #pragma unroll
            for (int nj = 0; nj < 4; ++nj)
                bf[nj] = lds_frag(Bs, wn * 64 + nj * 16 + r, ks * 64 + g * 16);
            #pragma unroll
            for (int mi = 0; mi < 2; ++mi)
                #pragma unroll
                for (int nj = 0; nj < 4; ++nj)
                    mfma16(acc[mi][nj], af[mi], bf[nj]);
        }
        __syncthreads();
    }
    #pragma unroll
    for (int nj = 0; nj < 4; ++nj) {
        int col = n0 + wn * 64 + nj * 16 + r;
        float bv_ = bo[col];
        #pragma unroll
        for (int mi = 0; mi < 2; ++mi) {
            acc_guard(acc[mi][nj]);
            #pragma unroll
            for (int j = 0; j < 4; ++j) {
                int row = m0 + wm * 32 + mi * 16 + g * 4 + j;
                Og[(size_t)row * 1024 + col] = acc[mi][nj][j] + bv_;
            }
        }
    }
}

// ---------------- MFMA attention v8: LDS-staged K/V + 3 blocks/CU ------------
// R17 structure (passing, 44us) with: (1) qr bias table in f16 (stride 50)
// -> LDS 55.8KB -> 49.4KB -> 3 blocks/CU (was 2); (2) Q pre-scaled in
// gemm_qkv -> softmax inner loop is one add + exp2 (no per-element mul).
#define QRH 50

__global__ __launch_bounds__(256, 3)
void attn_mfma(const short* __restrict__ qg, const short* __restrict__ kg,
               const short* __restrict__ vtg, const float* __restrict__ relk,
               const float* __restrict__ relv, short* __restrict__ xg) {
    __shared__ __align__(16) short k_s[64 * 64];      // 8KB, swizzled rows
    __shared__ __align__(16) short v_s[64 * 64];      // 8KB, V^T, swizzled
    __shared__ __align__(16) short p_s[4][16 * 72];   // 9216B, wave-local
    __shared__ short qr_h[64 * QRH];                  // 6400B, f16 bias table
    __shared__ float W_s[64 * NR];                    // 8448B
    __shared__ __align__(16) unsigned char relbuf[8976];
    short* rel_h = (short*)relbuf;    // [48][72] f16 (prologue)
    float* rv_s  = (float*)relbuf;    // [33][68] fp32 (epilogue)

    const int S = 1024, Dm = 1024;
    const int tid = threadIdx.x;
    const int wave = tid >> 6, lane = tid & 63;
    const int g = lane >> 4, r = lane & 15;
    const int blk = blockIdx.x;
    const int bh = blk & 31;      // same bh -> same XCD for K/V L2 reuse
    const int qb = blk >> 5;
    const int b = bh >> 4, h = bh & 15;
    const size_t base = (size_t)b * S * Dm + h * DH;
    const int qw = qb * 64 + wave * 16;
    const int qs = qb * 64;

    // staging geometry: chunk s = i*256+tid -> row = s>>3, LDS chunk c8 = s&7
    // LDS[row][c8] holds G[row][c8 ^ (row&7)] (16B units) == lds_frag layout.
    int srow[2], scol[2];
    #pragma unroll
    for (int i = 0; i < 2; ++i) {
        int s = i * 256 + tid;
        srow[i] = s >> 3;
        scol[i] = ((s & 7) ^ (srow[i] & 7)) << 3;
    }
    const short* kbase = kg + base;
    const short* vbase = vtg + (size_t)(bh * 64) * 1024;

    // prologue: load tile 0 into regs
    s16x8 kreg[2], vreg[2];
    #pragma unroll
    for (int i = 0; i < 2; ++i) {
        kreg[i] = *(const s16x8*)(kbase + (size_t)srow[i] * Dm + scol[i]);
        vreg[i] = *(const s16x8*)(vbase + (size_t)srow[i] * 1024 + scol[i]);
    }

    for (int idx = tid; idx < 48 * 64; idx += 256) {
        int row = idx >> 6, col = idx & 63;
        float val = (row < NR) ? relk[row * 64 + col] : 0.f;
        rel_h[row * 72 + col] = f2h(val);
    }
    for (int idx = tid; idx < 64 * NR; idx += 256) W_s[idx] = 0.f;
    __syncthreads();

    s16x8 qf[2];   // pre-scaled by log2(e)/8 in gemm_qkv
    qf[0] = *(const s16x8*)(qg + base + (size_t)(qw + r) * Dm + g * 8);
    qf[1] = *(const s16x8*)(qg + base + (size_t)(qw + r) * Dm + 32 + g * 8);

    // qr[q][bucket] = q_scaled . relk[bucket]  (auto-scaled); f16 store
    #pragma unroll
    for (int ct = 0; ct < 3; ++ct) {
        f32x4 c = {0.f, 0.f, 0.f, 0.f};
        s16x8 bf0 = *(const s16x8*)&rel_h[(ct * 16 + r) * 72 + g * 8];
        s16x8 bf1 = *(const s16x8*)&rel_h[(ct * 16 + r) * 72 + 32 + g * 8];
        mfma16(c, qf[0], bf0);
        mfma16_last(c, qf[1], bf1);
        #pragma unroll
        for (int j = 0; j < 4; ++j)
            qr_h[(wave * 16 + g * 4 + j) * QRH + ct * 16 + r] = f2h(c[j]);
    }
    __syncthreads();   // publish qr_h (in-loop reads are cross-lane)

    float bias0[4], bias32[4];
    #pragma unroll
    for (int j = 0; j < 4; ++j) {
        int qrow = wave * 16 + g * 4 + j;
        bias0[j]  = h2f(qr_h[qrow * QRH + 0]);
        bias32[j] = h2f(qr_h[qrow * QRH + 32]);
    }

    f32x4 acc[4] = {};
    #pragma unroll
    for (int dc = 0; dc < 4; ++dc)
        asm volatile("s_nop 7" : "+v"(acc[dc]));
    float l_acc[4] = {0.f, 0.f, 0.f, 0.f};
    float pre[4]   = {0.f, 0.f, 0.f, 0.f};
    float suf[4]   = {0.f, 0.f, 0.f, 0.f};

    for (int kt = 0; kt < S; kt += 64) {
        __syncthreads();   // previous tile's LDS reads complete
        #pragma unroll
        for (int i = 0; i < 2; ++i) {
            *(s16x8*)&k_s[(i * 256 + tid) * 8] = kreg[i];
            *(s16x8*)&v_s[(i * 256 + tid) * 8] = vreg[i];
        }
        __syncthreads();   // tile kt published

        if (kt < S - 64) {   // issue coalesced loads for t+1 (hidden by compute)
            #pragma unroll
            for (int i = 0; i < 2; ++i) {
                kreg[i] = *(const s16x8*)(kbase + (size_t)(kt + 64 + srow[i]) * Dm + scol[i]);
                vreg[i] = *(const s16x8*)(vbase + (size_t)srow[i] * 1024 + kt + 64 + scol[i]);
            }
        }

        const bool tlo = (kt <= qs - 128), thi = (kt >= qs + 128);
        #pragma unroll
        for (int kc = 0; kc < 4; ++kc) {
            s16x8 k0 = lds_frag(k_s, kc * 16 + r, g * 16);
            s16x8 k1 = lds_frag(k_s, kc * 16 + r, 64 + g * 16);
            f32x4 s = {0.f, 0.f, 0.f, 0.f};
            mfma16(s, qf[0], k0);
            mfma16_last(s, qf[1], k1);
            if (tlo) {
                #pragma unroll
                for (int j = 0; j < 4; ++j) {
                    float p = exp2f(s[j] + bias0[j]);
                    l_acc[j] += p; pre[j] += p;
                    p_s[wave][(g * 4 + j) * 72 + kc * 16 + r] = f2h(p);
                }
            } else if (thi) {
                #pragma unroll
                for (int j = 0; j < 4; ++j) {
                    float p = exp2f(s[j] + bias32[j]);
                    l_acc[j] += p; suf[j] += p;
                    p_s[wave][(g * 4 + j) * 72 + kc * 16 + r] = f2h(p);
                }
            } else {
                int k_abs = kt + kc * 16 + r;
                #pragma unroll
                for (int j = 0; j < 4; ++j) {
                    int qrow = wave * 16 + g * 4 + j;
                    int dist = k_abs - (qs + qrow);
                    int bkt = min(max(dist, -16), 16) + 16;
                    float p = exp2f(s[j] + h2f(qr_h[qrow * QRH + bkt]));
                    l_acc[j] += p;
                    if (dist <= -16)      pre[j] += p;
                    else if (dist >= 16)  suf[j] += p;
                    else                  W_s[qrow * NR + bkt] = p;
                    p_s[wave][(g * 4 + j) * 72 + kc * 16 + r] = f2h(p);
                }
            }
        }
        s16x8 pa0 = *(const s16x8*)&p_s[wave][r * 72 + g * 8];
        s16x8 pa1 = *(const s16x8*)&p_s[wave][r * 72 + 32 + g * 8];
        #pragma unroll
        for (int dc = 0; dc < 4; ++dc) {
            s16x8 v0 = lds_frag(v_s, dc * 16 + r, g * 16);
            s16x8 v1 = lds_frag(v_s, dc * 16 + r, 64 + g * 16);
            mfma16(acc[dc], pa0, v0);
            mfma16(acc[dc], pa1, v1);
        }
    }

    #pragma unroll
    for (int j = 0; j < 4; ++j) {
        #pragma unroll
        for (int m = 1; m < 16; m <<= 1) {
            l_acc[j] += __shfl_xor(l_acc[j], m, 16);
            pre[j]   += __shfl_xor(pre[j], m, 16);
            suf[j]   += __shfl_xor(suf[j], m, 16);
        }
    }
    if (r == 0) {
        #pragma unroll
        for (int j = 0; j < 4; ++j) {
            int qrow = wave * 16 + g * 4 + j;
            W_s[qrow * NR + 0]  = pre[j];
            W_s[qrow * NR + 32] = suf[j];
        }
    }

    __syncthreads();
    for (int idx = tid; idx < NR * 64; idx += 256)
        rv_s[(idx >> 6) * 68 + (idx & 63)] = relv[idx];
    __syncthreads();

    float R[4][4] = {};
    for (int rr = 0; rr < NR; ++rr) {
        float rvv[4];
        #pragma unroll
        for (int dc = 0; dc < 4; ++dc) rvv[dc] = rv_s[rr * 68 + dc * 16 + r];
        #pragma unroll
        for (int j = 0; j < 4; ++j) {
            float w = W_s[(wave * 16 + g * 4 + j) * NR + rr];
            #pragma unroll
            for (int dc = 0; dc < 4; ++dc) R[j][dc] = fmaf(w, rvv[dc], R[j][dc]);
        }
    }
    #pragma unroll
    for (int dc = 0; dc < 4; ++dc) acc_guard(acc[dc]);
    #pragma unroll
    for (int j = 0; j < 4; ++j) {
        float invl = 1.f / l_acc[j];
        size_t o = base + (size_t)(qw + g * 4 + j) * Dm;
        #pragma unroll
        for (int dc = 0; dc < 4; ++dc)
            xg[o + dc * 16 + r] = f2h((acc[dc][j] + R[j][dc]) * invl);
    }
}

// ---------------------------------------------------------------------------
extern "C" void kernel_launch(void* const* d_in, const int* in_sizes, int n_in,
                              void* d_out, int out_size, void* d_ws, size_t ws_size,
                              hipStream_t stream) {
    const float* query = (const float*)d_in[0];
    const float* key   = (const float*)d_in[1];
    const float* value = (const float*)d_in[2];
    const float* Wq    = (const float*)d_in[3];
    const float* bq    = (const float*)d_in[4];
    const float* Wk    = (const float*)d_in[5];
    const float* bk    = (const float*)d_in[6];
    const float* Wv    = (const float*)d_in[7];
    const float* bv    = (const float*)d_in[8];
    const float* Wo    = (const float*)d_in[9];
    const float* bo    = (const float*)d_in[10];
    const float* rel_k = (const float*)d_in[11];
    const float* rel_v = (const float*)d_in[12];

    // workspace (shorts): wt 4M | qkv 6M | x 2M | vt 2M = 28MB
    short* wt    = (short*)d_ws;
    short* qkv16 = wt + (size_t)4 * 1024 * 1024;
    short* x16   = qkv16 + (size_t)3 * 2048 * 1024;
    short* vt16  = x16 + (size_t)2048 * 1024;
    short* q16 = qkv16;
    short* k16 = qkv16 + (size_t)2048 * 1024;
    short* v16 = qkv16 + (size_t)2 * 2048 * 1024;

    cvt_w<<<dim3(32, 32, 4), 256, 0, stream>>>(Wq, Wk, Wv, Wo, wt);
    gemm_qkv<<<dim3(8, 96), 256, 0, stream>>>(query, key, value, wt,
                                              bq, bk, bv, qkv16);
    vT<<<dim3(16, 32), 256, 0, stream>>>(v16, vt16);
    attn_mfma<<<512, 256, 0, stream>>>(q16, k16, vt16, rel_k, rel_v, x16);
    gemm_out<<<dim3(8, 32), 256, 0, stream>>>(x16, wt + (size_t)3 * 1024 * 1024,
                                              bo, (float*)d_out);
}

// Round 19
// 100.099 us; speedup vs baseline: 1.0529x; 1.0529x over previous
//
#include <hip/hip_runtime.h>
#include <math.h>

#define Hh 16
#define DH 64
#define NR 33

typedef short s16x8 __attribute__((ext_vector_type(8)));
typedef float f32x4 __attribute__((ext_vector_type(4)));
typedef __fp16 h16x2 __attribute__((ext_vector_type(2)));
typedef __fp16 h16x8 __attribute__((ext_vector_type(8)));

static __device__ __forceinline__ short f2h(float f) {
    _Float16 h = (_Float16)f;              // RNE
    short s; __builtin_memcpy(&s, &h, 2); return s;
}
static __device__ __forceinline__ float h2f(short s) {
    _Float16 h; __builtin_memcpy(&h, &s, 2); return (float)h;
}
static __device__ __forceinline__ unsigned pk2h(float a, float b) {
    h16x2 h = __builtin_amdgcn_cvt_pkrtz(a, b);   // packed RTZ, 1 VALU op
    unsigned r; __builtin_memcpy(&r, &h, 4); return r;
}

// MFMA via builtin: LLVM's hazard recognizer inserts only the REQUIRED wait
// states and can schedule independent work into the latency shadows (the
// old inline-asm wrappers carried unconditional s_nop bundles -> ~80 dead
// cycles per attn tile and 4 nops per GEMM MFMA).
static __device__ __forceinline__ f32x4 mfma(f32x4 c, const s16x8& a, const s16x8& b) {
    h16x8 ah, bh;
    __builtin_memcpy(&ah, &a, 16);
    __builtin_memcpy(&bh, &b, 16);
    return __builtin_amdgcn_mfma_f32_16x16x32_f16(ah, bh, c, 0, 0, 0);
}

// async global->LDS, 16B/lane (GEMMs only — attn uses register staging)
static __device__ __forceinline__ void gld16(const short* g, short* l) {
    __builtin_amdgcn_global_load_lds(
        (const __attribute__((address_space(1))) void*)g,
        (__attribute__((address_space(3))) void*)l, 16, 0, 0);
}
static __device__ __forceinline__ void drain_vmem() {
    asm volatile("s_waitcnt vmcnt(0)" ::: "memory");
}

// swizzled fragment read: LDS[row][x] holds G[row][x ^ ((row&7)<<4)] (bytes)
static __device__ __forceinline__ s16x8 lds_frag(const short* base, int row, int kb) {
    return *(const s16x8*)((const char*)base + row * 128 + (kb ^ ((row & 7) << 4)));
}

// ---------------- weights: fp32 [K][N] -> f16 [N][K] ------------------------
__global__ __launch_bounds__(256)
void cvt_w(const float* __restrict__ W0, const float* __restrict__ W1,
           const float* __restrict__ W2, const float* __restrict__ W3,
           short* __restrict__ Wt) {
    __shared__ float ts[32][33];
    const int z = blockIdx.z;
    const float* W = (z == 0) ? W0 : (z == 1) ? W1 : (z == 2) ? W2 : W3;
    short* O = Wt + (size_t)z * 1024 * 1024;
    const int n0 = blockIdx.x * 32, k0 = blockIdx.y * 32;
    const int tx = threadIdx.x & 31, ty = threadIdx.x >> 5;
    #pragma unroll
    for (int rr = 0; rr < 4; ++rr)
        ts[ty + 8 * rr][tx] = W[(size_t)(k0 + ty + 8 * rr) * 1024 + n0 + tx];
    __syncthreads();
    #pragma unroll
    for (int rr = 0; rr < 4; ++rr)
        O[(size_t)(n0 + ty + 8 * rr) * 1024 + k0 + tx] = f2h(ts[tx][ty + 8 * rr]);
}

// ---------------- V^T: v16 [b][s][h*64+d] -> vt16 [(b*16+h)*64+d][s] --------
__global__ __launch_bounds__(256)
void vT(const short* __restrict__ v16, short* __restrict__ vt16) {
    __shared__ short ts[64][72];
    const int st = blockIdx.x;      // s-tile (16)
    const int bh = blockIdx.y;      // 32
    const int b = bh >> 4, h = bh & 15;
    const size_t inb = ((size_t)b * 1024 + st * 64) * 1024 + h * 64;
    #pragma unroll
    for (int i = 0; i < 2; ++i) {
        int chunk = i * 256 + threadIdx.x;
        int row = chunk >> 3, c8 = chunk & 7;
        *(s16x8*)&ts[row][c8 * 8] =
            *(const s16x8*)(v16 + inb + (size_t)row * 1024 + c8 * 8);
    }
    __syncthreads();
    const size_t outb = (size_t)(bh * 64) * 1024 + st * 64;
    #pragma unroll
    for (int i = 0; i < 2; ++i) {
        int chunk = i * 256 + threadIdx.x;
        int d = chunk >> 3, c8 = chunk & 7;
        s16x8 t;
        #pragma unroll
        for (int e = 0; e < 8; ++e) t[e] = ts[c8 * 8 + e][d];
        *(s16x8*)(vt16 + outb + (size_t)d * 1024 + c8 * 8) = t;
    }
}

// ---------------- fused QKV projection: f16 MFMA ----------------------------
// Slab 0 (Q) output is PRE-SCALED by log2(e)/sqrt(dh): QK^T scores and the
// qr bias then come out of the MFMA already scaled -> attn softmax is a
// single add + exp2 per element.
__global__ __launch_bounds__(256)
void gemm_qkv(const float* __restrict__ Aq, const float* __restrict__ Ak,
              const float* __restrict__ Av, const short* __restrict__ Wt,
              const float* __restrict__ bq, const float* __restrict__ bk,
              const float* __restrict__ bv, short* __restrict__ Out) {
    __shared__ __align__(16) short As[64 * 64];
    __shared__ __align__(16) short Bs[128 * 64];
    const int tid = threadIdx.x;
    const int wave = tid >> 6, lane = tid & 63;
    const int g = lane >> 4, r = lane & 15;
    const int wm = wave >> 1, wn = wave & 1;
    const int n0 = blockIdx.x * 128;
    const int by = blockIdx.y;
    const int slab = by >> 5;                 // 0:q 1:k 2:v
    const int m0 = (by & 31) * 64;
    const float* A    = (slab == 0) ? Aq : (slab == 1) ? Ak : Av;
    const float* bias = (slab == 0) ? bq : (slab == 1) ? bk : bv;
    const float osc   = (slab == 0) ? 0.18033688f : 1.0f;  // log2(e)/8 on Q
    const short* Bg = Wt + (size_t)slab * 1024 * 1024;
    short* Og = Out + (size_t)slab * 2048 * 1024;

    const int ar = tid >> 2, ak = tid & 3;
    const float* ap = A + (size_t)(m0 + ar) * 1024 + ak * 16;
    char* asb = (char*)As + ar * 128;
    const int aswz = (ar & 7) << 4;
    const int ao0 = (ak * 32) ^ aswz, ao1 = (ak * 32 + 16) ^ aswz;

    const short* bp[4]; short* bl[4];
    #pragma unroll
    for (int i = 0; i < 4; ++i) {
        int s = i * 256 + tid;
        int row = s >> 3, sk = s & 7;
        int gb = (sk * 16) ^ ((row & 7) << 4);
        bp[i] = Bg + (size_t)(n0 + row) * 1024 + gb / 2;
        bl[i] = Bs + (size_t)(i * 256 + wave * 64) * 8;
    }

    f32x4 acc[2][4] = {};

    for (int kt = 0; kt < 1024; kt += 64) {
        #pragma unroll
        for (int i = 0; i < 4; ++i) gld16(bp[i] + kt, bl[i]);
        float4 va[4];
        #pragma unroll
        for (int c = 0; c < 4; ++c) va[c] = *(const float4*)(ap + kt + c * 4);
        unsigned pk[8];
        #pragma unroll
        for (int c = 0; c < 4; ++c) {
            pk[2 * c]     = pk2h(va[c].x, va[c].y);
            pk[2 * c + 1] = pk2h(va[c].z, va[c].w);
        }
        *(uint4*)(asb + ao0) = *(const uint4*)&pk[0];
        *(uint4*)(asb + ao1) = *(const uint4*)&pk[4];
        drain_vmem();
        __syncthreads();
        #pragma unroll
        for (int ks = 0; ks < 2; ++ks) {
            s16x8 af[2], bf[4];
            #pragma unroll
            for (int mi = 0; mi < 2; ++mi)
                af[mi] = lds_frag(As, wm * 32 + mi * 16 + r, ks * 64 + g * 16);
            #pragma unroll
            for (int nj = 0; nj < 4; ++nj)
                bf[nj] = lds_frag(Bs, wn * 64 + nj * 16 + r, ks * 64 + g * 16);
            #pragma unroll
            for (int mi = 0; mi < 2; ++mi)
                #pragma unroll
                for (int nj = 0; nj < 4; ++nj)
                    acc[mi][nj] = mfma(acc[mi][nj], af[mi], bf[nj]);
        }
        __syncthreads();
    }
    #pragma unroll
    for (int nj = 0; nj < 4; ++nj) {
        int col = n0 + wn * 64 + nj * 16 + r;
        float bv_ = bias[col];
        #pragma unroll
        for (int mi = 0; mi < 2; ++mi) {
            #pragma unroll
            for (int j = 0; j < 4; ++j) {
                int row = m0 + wm * 32 + mi * 16 + g * 4 + j;
                Og[(size_t)row * 1024 + col] = f2h((acc[mi][nj][j] + bv_) * osc);
            }
        }
    }
}

// ---------------- output projection: x(f16) @ Wo_t(f16) + bo -> fp32 --------
__global__ __launch_bounds__(256)
void gemm_out(const short* __restrict__ Xg, const short* __restrict__ Bg,
              const float* __restrict__ bo, float* __restrict__ Og) {
    __shared__ __align__(16) short As[64 * 64];
    __shared__ __align__(16) short Bs[128 * 64];
    const int tid = threadIdx.x;
    const int wave = tid >> 6, lane = tid & 63;
    const int g = lane >> 4, r = lane & 15;
    const int wm = wave >> 1, wn = wave & 1;
    const int n0 = blockIdx.x * 128;
    const int m0 = blockIdx.y * 64;

    const short* xp[2]; short* xl[2];
    #pragma unroll
    for (int i = 0; i < 2; ++i) {
        int s = i * 256 + tid;
        int row = s >> 3, sk = s & 7;
        int gb = (sk * 16) ^ ((row & 7) << 4);
        xp[i] = Xg + (size_t)(m0 + row) * 1024 + gb / 2;
        xl[i] = As + (size_t)(i * 256 + wave * 64) * 8;
    }
    const short* bp[4]; short* bl[4];
    #pragma unroll
    for (int i = 0; i < 4; ++i) {
        int s = i * 256 + tid;
        int row = s >> 3, sk = s & 7;
        int gb = (sk * 16) ^ ((row & 7) << 4);
        bp[i] = Bg + (size_t)(n0 + row) * 1024 + gb / 2;
        bl[i] = Bs + (size_t)(i * 256 + wave * 64) * 8;
    }

    f32x4 acc[2][4] = {};

    for (int kt = 0; kt < 1024; kt += 64) {
        #pragma unroll
        for (int i = 0; i < 2; ++i) gld16(xp[i] + kt, xl[i]);
        #pragma unroll
        for (int i = 0; i < 4; ++i) gld16(bp[i] + kt, bl[i]);
        drain_vmem();
        __syncthreads();
        #pragma unroll
        for (int ks = 0; ks < 2; ++ks) {
            s16x8 af[2], bf[4];
            #pragma unroll
            for (int mi = 0; mi < 2; ++mi)
                af[mi] = lds_frag(As, wm * 32 + mi * 16 + r, ks * 64 + g * 16);
            #pragma unroll
            for (int nj = 0; nj < 4; ++nj)
                bf[nj] = lds_frag(Bs, wn * 64 + nj * 16 + r, ks * 64 + g * 16);
            #pragma unroll
            for (int mi = 0; mi < 2; ++mi)
                #pragma unroll
                for (int nj = 0; nj < 4; ++nj)
                    acc[mi][nj] = mfma(acc[mi][nj], af[mi], bf[nj]);
        }
        __syncthreads();
    }
    #pragma unroll
    for (int nj = 0; nj < 4; ++nj) {
        int col = n0 + wn * 64 + nj * 16 + r;
        float bv_ = bo[col];
        #pragma unroll
        for (int mi = 0; mi < 2; ++mi) {
            #pragma unroll
            for (int j = 0; j < 4; ++j) {
                int row = m0 + wm * 32 + mi * 16 + g * 4 + j;
                Og[(size_t)row * 1024 + col] = acc[mi][nj][j] + bv_;
            }
        }
    }
}

// ---------------- MFMA attention v9: builtin MFMA, no manual nops ------------
// R18 structure (passing, 44us): LDS-staged K/V via coalesced reg staging,
// f16 qr table, pre-scaled Q. MFMA now via builtin -> compiler fills the
// hazard wait slots with the softmax/staging work instead of dead s_nops.
#define QRH 50

__global__ __launch_bounds__(256, 2)
void attn_mfma(const short* __restrict__ qg, const short* __restrict__ kg,
               const short* __restrict__ vtg, const float* __restrict__ relk,
               const float* __restrict__ relv, short* __restrict__ xg) {
    __shared__ __align__(16) short k_s[64 * 64];      // 8KB, swizzled rows
    __shared__ __align__(16) short v_s[64 * 64];      // 8KB, V^T, swizzled
    __shared__ __align__(16) short p_s[4][16 * 72];   // 9216B, wave-local
    __shared__ short qr_h[64 * QRH];                  // 6400B, f16 bias table
    __shared__ float W_s[64 * NR];                    // 8448B
    __shared__ __align__(16) unsigned char relbuf[8976];
    short* rel_h = (short*)relbuf;    // [48][72] f16 (prologue)
    float* rv_s  = (float*)relbuf;    // [33][68] fp32 (epilogue)

    const int S = 1024, Dm = 1024;
    const int tid = threadIdx.x;
    const int wave = tid >> 6, lane = tid & 63;
    const int g = lane >> 4, r = lane & 15;
    const int blk = blockIdx.x;
    const int bh = blk & 31;      // same bh -> same XCD for K/V L2 reuse
    const int qb = blk >> 5;
    const int b = bh >> 4, h = bh & 15;
    const size_t base = (size_t)b * S * Dm + h * DH;
    const int qw = qb * 64 + wave * 16;
    const int qs = qb * 64;

    // staging geometry: chunk s = i*256+tid -> row = s>>3, LDS chunk c8 = s&7
    // LDS[row][c8] holds G[row][c8 ^ (row&7)] (16B units) == lds_frag layout.
    int srow[2], scol[2];
    #pragma unroll
    for (int i = 0; i < 2; ++i) {
        int s = i * 256 + tid;
        srow[i] = s >> 3;
        scol[i] = ((s & 7) ^ (srow[i] & 7)) << 3;
    }
    const short* kbase = kg + base;
    const short* vbase = vtg + (size_t)(bh * 64) * 1024;

    // prologue: load tile 0 into regs
    s16x8 kreg[2], vreg[2];
    #pragma unroll
    for (int i = 0; i < 2; ++i) {
        kreg[i] = *(const s16x8*)(kbase + (size_t)srow[i] * Dm + scol[i]);
        vreg[i] = *(const s16x8*)(vbase + (size_t)srow[i] * 1024 + scol[i]);
    }

    for (int idx = tid; idx < 48 * 64; idx += 256) {
        int row = idx >> 6, col = idx & 63;
        float val = (row < NR) ? relk[row * 64 + col] : 0.f;
        rel_h[row * 72 + col] = f2h(val);
    }
    for (int idx = tid; idx < 64 * NR; idx += 256) W_s[idx] = 0.f;
    __syncthreads();

    s16x8 qf[2];   // pre-scaled by log2(e)/8 in gemm_qkv
    qf[0] = *(const s16x8*)(qg + base + (size_t)(qw + r) * Dm + g * 8);
    qf[1] = *(const s16x8*)(qg + base + (size_t)(qw + r) * Dm + 32 + g * 8);

    // qr[q][bucket] = q_scaled . relk[bucket]  (auto-scaled); f16 store
    #pragma unroll
    for (int ct = 0; ct < 3; ++ct) {
        f32x4 c = {0.f, 0.f, 0.f, 0.f};
        s16x8 bf0 = *(const s16x8*)&rel_h[(ct * 16 + r) * 72 + g * 8];
        s16x8 bf1 = *(const s16x8*)&rel_h[(ct * 16 + r) * 72 + 32 + g * 8];
        c = mfma(c, qf[0], bf0);
        c = mfma(c, qf[1], bf1);
        #pragma unroll
        for (int j = 0; j < 4; ++j)
            qr_h[(wave * 16 + g * 4 + j) * QRH + ct * 16 + r] = f2h(c[j]);
    }
    __syncthreads();   // publish qr_h (in-loop reads are cross-lane)

    float bias0[4], bias32[4];
    #pragma unroll
    for (int j = 0; j < 4; ++j) {
        int qrow = wave * 16 + g * 4 + j;
        bias0[j]  = h2f(qr_h[qrow * QRH + 0]);
        bias32[j] = h2f(qr_h[qrow * QRH + 32]);
    }

    f32x4 acc[4] = {};
    float l_acc[4] = {0.f, 0.f, 0.f, 0.f};
    float pre[4]   = {0.f, 0.f, 0.f, 0.f};
    float suf[4]   = {0.f, 0.f, 0.f, 0.f};

    for (int kt = 0; kt < S; kt += 64) {
        __syncthreads();   // previous tile's LDS reads complete
        #pragma unroll
        for (int i = 0; i < 2; ++i) {
            *(s16x8*)&k_s[(i * 256 + tid) * 8] = kreg[i];
            *(s16x8*)&v_s[(i * 256 + tid) * 8] = vreg[i];
        }
        __syncthreads();   // tile kt published

        if (kt < S - 64) {   // issue coalesced loads for t+1 (hidden by compute)
            #pragma unroll
            for (int i = 0; i < 2; ++i) {
                kreg[i] = *(const s16x8*)(kbase + (size_t)(kt + 64 + srow[i]) * Dm + scol[i]);
                vreg[i] = *(const s16x8*)(vbase + (size_t)srow[i] * 1024 + kt + 64 + scol[i]);
            }
        }

        const bool tlo = (kt <= qs - 128), thi = (kt >= qs + 128);
        #pragma unroll
        for (int kc = 0; kc < 4; ++kc) {
            s16x8 k0 = lds_frag(k_s, kc * 16 + r, g * 16);
            s16x8 k1 = lds_frag(k_s, kc * 16 + r, 64 + g * 16);
            f32x4 s = {0.f, 0.f, 0.f, 0.f};
            s = mfma(s, qf[0], k0);
            s = mfma(s, qf[1], k1);
            if (tlo) {
                #pragma unroll
                for (int j = 0; j < 4; ++j) {
                    float p = exp2f(s[j] + bias0[j]);
                    l_acc[j] += p; pre[j] += p;
                    p_s[wave][(g * 4 + j) * 72 + kc * 16 + r] = f2h(p);
                }
            } else if (thi) {
                #pragma unroll
                for (int j = 0; j < 4; ++j) {
                    float p = exp2f(s[j] + bias32[j]);
                    l_acc[j] += p; suf[j] += p;
                    p_s[wave][(g * 4 + j) * 72 + kc * 16 + r] = f2h(p);
                }
            } else {
                int k_abs = kt + kc * 16 + r;
                #pragma unroll
                for (int j = 0; j < 4; ++j) {
                    int qrow = wave * 16 + g * 4 + j;
                    int dist = k_abs - (qs + qrow);
                    int bkt = min(max(dist, -16), 16) + 16;
                    float p = exp2f(s[j] + h2f(qr_h[qrow * QRH + bkt]));
                    l_acc[j] += p;
                    if (dist <= -16)      pre[j] += p;
                    else if (dist >= 16)  suf[j] += p;
                    else                  W_s[qrow * NR + bkt] = p;
                    p_s[wave][(g * 4 + j) * 72 + kc * 16 + r] = f2h(p);
                }
            }
        }
        s16x8 pa0 = *(const s16x8*)&p_s[wave][r * 72 + g * 8];
        s16x8 pa1 = *(const s16x8*)&p_s[wave][r * 72 + 32 + g * 8];
        #pragma unroll
        for (int dc = 0; dc < 4; ++dc) {
            s16x8 v0 = lds_frag(v_s, dc * 16 + r, g * 16);
            s16x8 v1 = lds_frag(v_s, dc * 16 + r, 64 + g * 16);
            acc[dc] = mfma(acc[dc], pa0, v0);
            acc[dc] = mfma(acc[dc], pa1, v1);
        }
    }

    #pragma unroll
    for (int j = 0; j < 4; ++j) {
        #pragma unroll
        for (int m = 1; m < 16; m <<= 1) {
            l_acc[j] += __shfl_xor(l_acc[j], m, 16);
            pre[j]   += __shfl_xor(pre[j], m, 16);
            suf[j]   += __shfl_xor(suf[j], m, 16);
        }
    }
    if (r == 0) {
        #pragma unroll
        for (int j = 0; j < 4; ++j) {
            int qrow = wave * 16 + g * 4 + j;
            W_s[qrow * NR + 0]  = pre[j];
            W_s[qrow * NR + 32] = suf[j];
        }
    }

    __syncthreads();
    for (int idx = tid; idx < NR * 64; idx += 256)
        rv_s[(idx >> 6) * 68 + (idx & 63)] = relv[idx];
    __syncthreads();

    float R[4][4] = {};
    for (int rr = 0; rr < NR; ++rr) {
        float rvv[4];
        #pragma unroll
        for (int dc = 0; dc < 4; ++dc) rvv[dc] = rv_s[rr * 68 + dc * 16 + r];
        #pragma unroll
        for (int j = 0; j < 4; ++j) {
            float w = W_s[(wave * 16 + g * 4 + j) * NR + rr];
            #pragma unroll
            for (int dc = 0; dc < 4; ++dc) R[j][dc] = fmaf(w, rvv[dc], R[j][dc]);
        }
    }
    #pragma unroll
    for (int j = 0; j < 4; ++j) {
        float invl = 1.f / l_acc[j];
        size_t o = base + (size_t)(qw + g * 4 + j) * Dm;
        #pragma unroll
        for (int dc = 0; dc < 4; ++dc)
            xg[o + dc * 16 + r] = f2h((acc[dc][j] + R[j][dc]) * invl);
    }
}

// ---------------------------------------------------------------------------
extern "C" void kernel_launch(void* const* d_in, const int* in_sizes, int n_in,
                              void* d_out, int out_size, void* d_ws, size_t ws_size,
                              hipStream_t stream) {
    const float* query = (const float*)d_in[0];
    const float* key   = (const float*)d_in[1];
    const float* value = (const float*)d_in[2];
    const float* Wq    = (const float*)d_in[3];
    const float* bq    = (const float*)d_in[4];
    const float* Wk    = (const float*)d_in[5];
    const float* bk    = (const float*)d_in[6];
    const float* Wv    = (const float*)d_in[7];
    const float* bv    = (const float*)d_in[8];
    const float* Wo    = (const float*)d_in[9];
    const float* bo    = (const float*)d_in[10];
    const float* rel_k = (const float*)d_in[11];
    const float* rel_v = (const float*)d_in[12];

    // workspace (shorts): wt 4M | qkv 6M | x 2M | vt 2M = 28MB
    short* wt    = (short*)d_ws;
    short* qkv16 = wt + (size_t)4 * 1024 * 1024;
    short* x16   = qkv16 + (size_t)3 * 2048 * 1024;
    short* vt16  = x16 + (size_t)2048 * 1024;
    short* q16 = qkv16;
    short* k16 = qkv16 + (size_t)2048 * 1024;
    short* v16 = qkv16 + (size_t)2 * 2048 * 1024;

    cvt_w<<<dim3(32, 32, 4), 256, 0, stream>>>(Wq, Wk, Wv, Wo, wt);
    gemm_qkv<<<dim3(8, 96), 256, 0, stream>>>(query, key, value, wt,
                                              bq, bk, bv, qkv16);
    vT<<<dim3(16, 32), 256, 0, stream>>>(v16, vt16);
    attn_mfma<<<512, 256, 0, stream>>>(q16, k16, vt16, rel_k, rel_v, x16);
    gemm_out<<<dim3(8, 32), 256, 0, stream>>>(x16, wt + (size_t)3 * 1024 * 1024,
                                              bo, (float*)d_out);
}